// Round 5
// baseline (131.105 us; speedup 1.0000x reference)
//
#include <hip/hip_runtime.h>
#include <math.h>

#define NB   8
#define TD   64
#define TE   1024
#define DDIM 256
#define UDIM 128
#define NSG  8      // s-slices per batch
#define SLEN 128    // s per slice
#define NTG  4      // t-groups per batch
#define TLEN 16     // t per group

__device__ __forceinline__ float rcp_fast(float x) {
    return __builtin_amdgcn_rcpf(x);   // v_rcp_f32 — fine downstream of softmax
}

// ---------------------------------------------------------------------------
// Kernel 1: E = exp(2*(X @ W + b)).
//   encoder -> E_T4[b][uq(32)][s(1024)] as float4 (u-quad per s): k_fused's
//              per-uq load is one coalesced dwordx4 per lane.
//   decoder -> E_dec[t][u] row layout (read via s_load in k_fused).
// tanh(a+c) = 1 - 2/(e^{2a} e^{2c} + 1) -> store e^{2w} once per row.
// ---------------------------------------------------------------------------
__global__ __launch_bounds__(256) void k_compute_E(
    const float* __restrict__ enc, const float* __restrict__ dec,
    const float* __restrict__ W1, const float* __restrict__ b1,
    const float* __restrict__ W2, const float* __restrict__ b2,
    float* __restrict__ E_T, float* __restrict__ E_dec)
{
    __shared__ alignas(16) float ldsT[DDIM][20];  // [d][r], r<16, pad->20

    const int blk = blockIdx.x;
    const int tid = threadIdx.x;
    const float k2l2e = 2.0f * 1.4426950408889634f;  // 2*log2(e)

    if (blk < 512) {
        // ---------------- encoder path: write u-quad-transposed ----------
        const int b    = blk >> 6;
        const int row0 = (blk & 63) * 16;
        const float* in = enc + ((size_t)b * TE + row0) * DDIM;

        for (int i = tid; i < 16 * DDIM; i += 256) {
            ldsT[i & 255][i >> 8] = in[i];
        }
        __syncthreads();

        const int uq = tid >> 3;          // 0..31 u-quad
        const int rr = (tid & 7) * 2;     // row-pair 0,2,..,14
        const int u0 = uq * 4;

        float4 A0 = make_float4(0.f, 0.f, 0.f, 0.f);
        float4 A1 = make_float4(0.f, 0.f, 0.f, 0.f);

        #pragma unroll 8
        for (int d = 0; d < DDIM; ++d) {
            const float4 w4 = *(const float4*)(W1 + d * UDIM + u0);
            const float2 a2 = *(const float2*)(&ldsT[d][rr]);   // broadcast
            A0.x = fmaf(a2.x, w4.x, A0.x); A1.x = fmaf(a2.y, w4.x, A1.x);
            A0.y = fmaf(a2.x, w4.y, A0.y); A1.y = fmaf(a2.y, w4.y, A1.y);
            A0.z = fmaf(a2.x, w4.z, A0.z); A1.z = fmaf(a2.y, w4.z, A1.z);
            A0.w = fmaf(a2.x, w4.w, A0.w); A1.w = fmaf(a2.y, w4.w, A1.w);
        }

        const float4 bb = *(const float4*)(b1 + u0);
        float4 q0, q1;
        q0.x = exp2f((A0.x + bb.x) * k2l2e);  q1.x = exp2f((A1.x + bb.x) * k2l2e);
        q0.y = exp2f((A0.y + bb.y) * k2l2e);  q1.y = exp2f((A1.y + bb.y) * k2l2e);
        q0.z = exp2f((A0.z + bb.z) * k2l2e);  q1.z = exp2f((A1.z + bb.z) * k2l2e);
        q0.w = exp2f((A0.w + bb.w) * k2l2e);  q1.w = exp2f((A1.w + bb.w) * k2l2e);

        float4* E_T4 = (float4*)E_T;
        const size_t qbase = ((size_t)b * 32 + uq) * TE + row0 + rr;
        E_T4[qbase]     = q0;
        E_T4[qbase + 1] = q1;
    } else {
        // ---------------- decoder path: row layout -----------------------
        const int bd = blk - 512;
        const float* in = dec + (size_t)bd * 16 * DDIM;
        float* out = E_dec + (size_t)bd * 16 * UDIM;

        for (int i = tid; i < 16 * DDIM; i += 256) {
            ldsT[i & 255][i >> 8] = in[i];
        }
        __syncthreads();

        const int u0 = (tid & 63) * 2;
        const int r0 = (tid >> 6) * 4;

        float acc[4][2];
        #pragma unroll
        for (int r = 0; r < 4; ++r) { acc[r][0] = 0.f; acc[r][1] = 0.f; }

        #pragma unroll 8
        for (int d = 0; d < DDIM; ++d) {
            const float2 w2 = *(const float2*)(W2 + d * UDIM + u0);
            const float4 a4 = *(const float4*)(&ldsT[d][r0]);
            acc[0][0] = fmaf(a4.x, w2.x, acc[0][0]); acc[0][1] = fmaf(a4.x, w2.y, acc[0][1]);
            acc[1][0] = fmaf(a4.y, w2.x, acc[1][0]); acc[1][1] = fmaf(a4.y, w2.y, acc[1][1]);
            acc[2][0] = fmaf(a4.z, w2.x, acc[2][0]); acc[2][1] = fmaf(a4.z, w2.y, acc[2][1]);
            acc[3][0] = fmaf(a4.w, w2.x, acc[3][0]); acc[3][1] = fmaf(a4.w, w2.y, acc[3][1]);
        }

        const float bb0 = b2[u0], bb1 = b2[u0 + 1];
        #pragma unroll
        for (int r = 0; r < 4; ++r) {
            const float e0 = exp2f((acc[r][0] + bb0) * k2l2e);
            const float e1 = exp2f((acc[r][1] + bb1) * k2l2e);
            *(float2*)(out + (size_t)(r0 + r) * UDIM + u0) = make_float2(e0, e1);
        }
    }
}

// ---------------------------------------------------------------------------
// Kernel 2: flash-style tile. Block = (b, tg of 16 t, sg of 128 s), 1024 thr.
// Phase A: 16x128 score tile -> LDS.
//          score'(t,s) = -2 * sum_u V_u * rcp(1 + E_s E_t)   (tanh identity;
//          constant shift sum(V)+bV cancels in softmax).
// Partial softmax over the 128-s slice: per-t local max m + local sum l -> ml.
// Phase B: partial context (16t x 256d) against enc s-slice -> part.
// ---------------------------------------------------------------------------
__global__ __launch_bounds__(1024) void k_fused2(
    const float* __restrict__ E_T, const float* __restrict__ E_dec,
    const float* __restrict__ V, const float* __restrict__ enc,
    float2* __restrict__ ml, float* __restrict__ part)
{
    __shared__ float sc[TLEN][SLEN];    // 8 KB: scores, then p-values

    const int blk = blockIdx.x;         // 0..255
    const int b   = blk >> 5;
    const int tg  = (blk >> 3) & 3;
    const int sg  = blk & 7;
    const int tid = threadIdx.x;

    // ---- Phase A: scores for 16 t x 128 s ----
    const int sl = tid & 127;
    const int th = __builtin_amdgcn_readfirstlane(tid >> 7);   // 0..7, SGPR
    const int sglob = sg * SLEN + sl;

    const float4* e4  = (const float4*)E_T + (size_t)b * 32 * TE + sglob;
    const float*  er0 = E_dec + (size_t)(b * TD + tg * TLEN + th) * UDIM;  // uniform
    const float*  er1 = er0 + 8 * UDIM;                                    // t+8

    float acc0 = 0.f, acc1 = 0.f;
    #pragma unroll 8
    for (int uq = 0; uq < 32; ++uq) {
        const float4 e = e4[(size_t)uq * TE];    // coalesced dwordx4
        const int u0 = uq * 4;
        const float v0 = V[u0], v1 = V[u0+1], v2 = V[u0+2], v3 = V[u0+3];  // s_load
        acc0 = fmaf(v0, rcp_fast(fmaf(e.x, er0[u0  ], 1.f)), acc0);
        acc1 = fmaf(v0, rcp_fast(fmaf(e.x, er1[u0  ], 1.f)), acc1);
        acc0 = fmaf(v1, rcp_fast(fmaf(e.y, er0[u0+1], 1.f)), acc0);
        acc1 = fmaf(v1, rcp_fast(fmaf(e.y, er1[u0+1], 1.f)), acc1);
        acc0 = fmaf(v2, rcp_fast(fmaf(e.z, er0[u0+2], 1.f)), acc0);
        acc1 = fmaf(v2, rcp_fast(fmaf(e.z, er1[u0+2], 1.f)), acc1);
        acc0 = fmaf(v3, rcp_fast(fmaf(e.w, er0[u0+3], 1.f)), acc0);
        acc1 = fmaf(v3, rcp_fast(fmaf(e.w, er1[u0+3], 1.f)), acc1);
    }
    sc[th][sl]     = -2.0f * acc0;
    sc[th + 8][sl] = -2.0f * acc1;
    __syncthreads();

    // ---- partial softmax per t-row over this 128-s slice ----
    const int tw = __builtin_amdgcn_readfirstlane(tid >> 6);   // 0..15
    const int ln = tid & 63;
    const float v0s = sc[tw][ln];
    const float v1s = sc[tw][ln + 64];
    float m = fmaxf(v0s, v1s);
    #pragma unroll
    for (int off = 32; off; off >>= 1) m = fmaxf(m, __shfl_xor(m, off));
    const float p0 = __expf(v0s - m);
    const float p1 = __expf(v1s - m);
    float l = p0 + p1;
    #pragma unroll
    for (int off = 32; off; off >>= 1) l += __shfl_xor(l, off);
    sc[tw][ln]      = p0;      // same slots this thread read — no race
    sc[tw][ln + 64] = p1;
    if (ln == 0)
        ml[(size_t)(b * TD + tg * TLEN + tw) * NSG + sg] = make_float2(m, l);
    __syncthreads();

    // ---- Phase B: partial context against enc s-slice ----
    const int dp = tid & 127;  const int d0 = dp * 2;
    const int tq = __builtin_amdgcn_readfirstlane(tid >> 7);   // 0..7 -> 2 t each
    const float* eb = enc + ((size_t)(b * TE + sg * SLEN)) * DDIM + d0;

    float c00 = 0.f, c01 = 0.f, c10 = 0.f, c11 = 0.f;
    #pragma unroll 4
    for (int s = 0; s < SLEN; ++s) {
        const float2 e = *(const float2*)(eb + (size_t)s * DDIM);
        const float a0 = sc[tq * 2][s];          // LDS broadcast
        const float a1 = sc[tq * 2 + 1][s];      // LDS broadcast
        c00 = fmaf(a0, e.x, c00); c01 = fmaf(a0, e.y, c01);
        c10 = fmaf(a1, e.x, c10); c11 = fmaf(a1, e.y, c11);
    }
    const int trow = tg * TLEN + tq * 2;
    float* pb = part + (((size_t)(b * NSG + sg) * TD) + trow) * DDIM + d0;
    *(float2*)pb          = make_float2(c00, c01);
    *(float2*)(pb + DDIM) = make_float2(c10, c11);
}

// ---------------------------------------------------------------------------
// Kernel 3: combine s-slice partials (flash-attention reweighting).
// Block = one (b,t) row, 256 threads = d.
// ---------------------------------------------------------------------------
__global__ __launch_bounds__(256) void k_combine(
    const float2* __restrict__ ml, const float* __restrict__ part,
    float* __restrict__ out)
{
    const int bt = blockIdx.x;          // 0..511
    const int d  = threadIdx.x;
    const int b  = bt >> 6, t = bt & 63;

    float2 mls[NSG];
    float m_g = -3.4e38f;
    #pragma unroll
    for (int sg = 0; sg < NSG; ++sg) {
        mls[sg] = ml[(size_t)bt * NSG + sg];
        m_g = fmaxf(m_g, mls[sg].x);
    }
    float l_g = 0.f;
    float w[NSG];
    #pragma unroll
    for (int sg = 0; sg < NSG; ++sg) {
        w[sg] = __expf(mls[sg].x - m_g);
        l_g = fmaf(mls[sg].y, w[sg], l_g);
    }
    const float inv = rcp_fast(l_g);

    float r = 0.f;
    #pragma unroll
    for (int sg = 0; sg < NSG; ++sg)
        r = fmaf(part[(((size_t)(b * NSG + sg) * TD) + t) * DDIM + d], w[sg], r);
    out[(size_t)bt * DDIM + d] = r * inv;
}

extern "C" void kernel_launch(void* const* d_in, const int* in_sizes, int n_in,
                              void* d_out, int out_size, void* d_ws, size_t ws_size,
                              hipStream_t stream) {
    const float* dec = (const float*)d_in[0];   // [8,64,256]
    const float* enc = (const float*)d_in[1];   // [8,1024,256]
    const float* W1  = (const float*)d_in[2];   // [256,128]
    const float* b1  = (const float*)d_in[3];   // [128]
    const float* W2  = (const float*)d_in[4];   // [256,128]
    const float* b2  = (const float*)d_in[5];   // [128]
    const float* V   = (const float*)d_in[6];   // [128,1]
    // d_in[7] = bV: constant shift, cancels in softmax -> unused.

    float*  ws    = (float*)d_ws;
    float*  E_T   = ws;                                   // 8*128*1024  = 1048576 f
    float*  E_dec = E_T + (size_t)NB * UDIM * TE;         // 512*128     =   65536 f
    float2* ml    = (float2*)(E_dec + (size_t)512 * UDIM);// 8*64*8      =    4096 f2
    float*  part  = (float*)(ml + (size_t)NB * TD * NSG); // 8*8*64*256  = 1048576 f
    // total ws use ~ 8.7 MB

    k_compute_E<<<544, 256,  0, stream>>>(enc, dec, W1, b1, W2, b2, E_T, E_dec);
    k_fused2   <<<256, 1024, 0, stream>>>(E_T, E_dec, V, enc, ml, part);
    k_combine  <<<512, 256,  0, stream>>>(ml, part, (float*)d_out);
}